// Round 2
// baseline (710.379 us; speedup 1.0000x reference)
//
#include <hip/hip_runtime.h>

#define KE_CONST 14.3996454784255f

#define P2_SHIFT 15
#define P2_CHUNK 32768            // 128 KB LDS accumulator per chunk (scan phase)
#define MAXC     4
#define MAXE     16               // pair table up to 256 entries (4 KB LDS)
#define ELEM_CAP 131072           // 128 KB LDS elem table cap
#define GRID_B   256              // one block per CU (LDS-forced), co-resident
#define THR      1024

// ---------------- grid barrier (co-resident by construction: 135KB LDS => 1 blk/CU,
// grid == CU count). Device-scope release/acquire around an agent-scope counter. ----
__device__ __forceinline__ void grid_bar(unsigned* bar, unsigned target) {
    __syncthreads();
    __threadfence();                                   // release: drain writes device-wide
    if (threadIdx.x == 0) {
        __hip_atomic_fetch_add(bar, 1u, __ATOMIC_ACQ_REL, __HIP_MEMORY_SCOPE_AGENT);
        unsigned spin = 0;
        while (__hip_atomic_load(bar, __ATOMIC_ACQUIRE, __HIP_MEMORY_SCOPE_AGENT) < target
               && ++spin < 100000000u)
            __builtin_amdgcn_s_sleep(1);
    }
    __syncthreads();
    __threadfence();                                   // acquire side
}

// ---------------- deterministic proportional block allocation for the scan ----------
__device__ __forceinline__ void scan_alloc(const unsigned* __restrict__ g_,
        int& nb0, int& nb1, int& nb2, int& nb3,
        int& st1, int& st2, int& st3,
        long long& cs1, long long& cs2, long long& cs3,
        long long& g0, long long& g1, long long& g2, long long& g3) {
    g0 = g_[0]; g1 = g_[1]; g2 = g_[2]; g3 = g_[3];
    long long tot = g0 + g1 + g2 + g3; if (tot < 1) tot = 1;
    nb0 = (int)((g0 * GRID_B) / tot); if (nb0 < 1) nb0 = 1;
    nb1 = (int)((g1 * GRID_B) / tot); if (nb1 < 1) nb1 = 1;
    nb2 = (int)((g2 * GRID_B) / tot); if (nb2 < 1) nb2 = 1;
    nb3 = (int)((g3 * GRID_B) / tot); if (nb3 < 1) nb3 = 1;
    int sum = nb0 + nb1 + nb2 + nb3;
    while (sum > GRID_B) {
        if      (nb0 >= nb1 && nb0 >= nb2 && nb0 >= nb3) nb0--;
        else if (nb1 >= nb2 && nb1 >= nb3)               nb1--;
        else if (nb2 >= nb3)                             nb2--;
        else                                             nb3--;
        sum--;
    }
    while (sum < GRID_B) {
        if      (nb0 >= nb1 && nb0 >= nb2 && nb0 >= nb3) nb0++;
        else if (nb1 >= nb2 && nb1 >= nb3)               nb1++;
        else if (nb2 >= nb3)                             nb2++;
        else                                             nb3++;
        sum++;
    }
    st1 = nb0; st2 = nb0 + nb1; st3 = nb0 + nb1 + nb2;
    cs1 = g0;  cs2 = g0 + g1;   cs3 = g0 + g1 + g2;
}

// ---------------- per-edge bf16 value from pair-table entry ----------------
__device__ __forceinline__ unsigned enc_val16(float xv, const float4& p) {
    float t = xv * p.x;
    float phi = 0.1818f  * __expf(-3.2f    * t)
              + 0.5099f  * __expf(-0.9423f * t)
              + 0.2802f  * __expf(-0.4028f * t)
              + 0.02817f * __expf(-0.2016f * t);
    float rr = xv * p.w;
    float r2 = rr * rr;
    float r6 = r2 * r2 * r2;
    float env = 1.0f - 28.0f * r6 + 48.0f * r6 * rr - 21.0f * r6 * r2;
    float val = fmaxf(p.y * phi / xv * env, 0.0f);
    unsigned e = (__float_as_uint(val) + 0x8000u) >> 16;   // round-to-nearest bf16
    return (xv < p.z) ? e : 0u;
}

// ---------------- wave-aggregated bucketed scatter (<=4 LDS atomics / wave-round) ----
__device__ __forceinline__ void scatter_bal(unsigned rw, float xv, const float4& p,
                                            unsigned* cur, const unsigned* seg,
                                            unsigned* __restrict__ packedB, int lane) {
    unsigned cc = rw >> P2_SHIFT;
    unsigned w  = ((rw & (P2_CHUNK - 1)) << 16) | enc_val16(xv, p);
    unsigned long long m0 = __ballot(cc == 0), m1 = __ballot(cc == 1),
                       m2 = __ballot(cc == 2), m3 = __ballot(cc == 3);
    unsigned long long mine = (cc == 0) ? m0 : (cc == 1) ? m1 : (cc == 2) ? m2 : m3;
    int ldr = __ffsll((long long)mine) - 1;
    unsigned base = 0;
    if (lane == ldr) base = atomicAdd(&cur[cc], (unsigned)__popcll(mine));
    base = __shfl(base, ldr, 64);
    unsigned pos = base + (unsigned)__popcll(mine & ((1ull << lane) - 1ull));
    packedB[(size_t)seg[cc] + pos] = w;
}

#define ACC1(W) { if ((W) & 0xFFFFu) \
    atomicAdd(&acc[(W) >> 16], __uint_as_float(((W) & 0xFFFFu) << 16)); }
#define ACC4(Q) { ACC1((Q).x); ACC1((Q).y); ACC1((Q).z); ACC1((Q).w); }

// =================== single fused persistent kernel ===================
__global__ __launch_bounds__(THR)
void zbl_fused(const float* __restrict__ x,
               const float* __restrict__ node_attrs,
               const int* __restrict__ ei,
               const int* __restrict__ atomic_numbers,
               const float* __restrict__ covalent_radii,
               unsigned char* __restrict__ elem_g,
               unsigned* __restrict__ meta,     // [0..3]=gcount, [16]=barrier
               unsigned* __restrict__ packedB,
               float* __restrict__ partial,
               float* __restrict__ out,
               int n_edges, int n_elem, int n_nodes) {
    __shared__ __align__(16) unsigned char smem[ELEM_CAP];   // elem table -> f32 acc
    __shared__ float4 pt[MAXE * MAXE];
    __shared__ unsigned mh[MAXC];     // histogram, then scatter cursors
    __shared__ unsigned mpos[MAXC];   // this block's reserved in-bucket base
    __shared__ unsigned mseg[MAXC];   // this block's absolute segment base

    unsigned* gcount = meta;
    unsigned* bar    = meta + 16;
    const int b = blockIdx.x, t = threadIdx.x, lane = t & 63;

    // ---------- P0: pair table (redundant per block), elem slice -> global ----------
    int np = n_elem * n_elem;
    for (int i = t; i < np; i += THR) {
        int eu = i / n_elem, ev = i - eu * n_elem;
        int Zu = atomic_numbers[eu], Zv = atomic_numbers[ev];
        float zu = (float)Zu, zv = (float)Zv;
        float inv_a = (__powf(zu, 0.3f) + __powf(zv, 0.3f)) * (1.0f / (0.4543f * 0.529f));
        float rmax  = covalent_radii[Zu] + covalent_radii[Zv];
        pt[i] = make_float4(inv_a, 0.5f * KE_CONST * zu * zv, rmax, 1.0f / rmax);
    }
    {
        int n0 = (int)(((long long)b * n_nodes) / GRID_B);
        int n1 = (int)(((long long)(b + 1) * n_nodes) / GRID_B);
        for (int n = n0 + t; n < n1; n += THR) {
            const float* row = node_attrs + (size_t)n * n_elem;
            float best = row[0]; int bi = 0;
            for (int i2 = 1; i2 < n_elem; ++i2) {
                float v = row[i2];
                if (v > best) { best = v; bi = i2; }
            }
            elem_g[n] = (unsigned char)bi;
        }
    }
    if (t < MAXC) mh[t] = 0u;
    grid_bar(bar, 1 * GRID_B);                       // S1

    // ---------- P1: elem -> LDS ; count receivers ; reserve bucket segments ----------
    {
        int nwords = (n_nodes + 15) >> 4;
        const uint4* eg4 = (const uint4*)elem_g;
        uint4* el4 = (uint4*)smem;
        for (int i = t; i < nwords; i += THR) el4[i] = eg4[i];
    }
    long long e0 = (((long long)b * n_edges) / GRID_B) & ~3LL;
    long long e1 = (b == GRID_B - 1) ? (long long)n_edges
                 : ((((long long)(b + 1) * n_edges) / GRID_B) & ~3LL);
    {
        const int* r = ei + n_edges;
        unsigned c0 = 0, c1 = 0, c2 = 0, c3 = 0;
        long long vend = e1 & ~3LL;
        for (long long p = e0 + (long long)t * 4; p + 4 <= vend; p += (long long)THR * 4) {
            int4 a = *(const int4*)(r + p);
            unsigned cc;
            cc = ((unsigned)a.x) >> P2_SHIFT; c0 += (cc==0); c1 += (cc==1); c2 += (cc==2); c3 += (cc==3);
            cc = ((unsigned)a.y) >> P2_SHIFT; c0 += (cc==0); c1 += (cc==1); c2 += (cc==2); c3 += (cc==3);
            cc = ((unsigned)a.z) >> P2_SHIFT; c0 += (cc==0); c1 += (cc==1); c2 += (cc==2); c3 += (cc==3);
            cc = ((unsigned)a.w) >> P2_SHIFT; c0 += (cc==0); c1 += (cc==1); c2 += (cc==2); c3 += (cc==3);
        }
        for (long long e2 = vend + t; e2 < e1; e2 += THR) {
            unsigned cc = ((unsigned)r[e2]) >> P2_SHIFT;
            c0 += (cc==0); c1 += (cc==1); c2 += (cc==2); c3 += (cc==3);
        }
        for (int o = 32; o; o >>= 1) {
            c0 += __shfl_down(c0, o, 64); c1 += __shfl_down(c1, o, 64);
            c2 += __shfl_down(c2, o, 64); c3 += __shfl_down(c3, o, 64);
        }
        if (lane == 0) {
            atomicAdd(&mh[0], c0); atomicAdd(&mh[1], c1);
            atomicAdd(&mh[2], c2); atomicAdd(&mh[3], c3);
        }
    }
    __syncthreads();
    if (t < MAXC) mpos[t] = atomicAdd(&gcount[t], mh[t]);
    grid_bar(bar, 2 * GRID_B);                       // S2

    // ---------- P2: dense compute + bucketed scatter ----------
    {
        if (t == 0) {
            unsigned g0 = gcount[0], g1 = gcount[1], g2 = gcount[2];
            mseg[0] = mpos[0];
            mseg[1] = g0 + mpos[1];
            mseg[2] = g0 + g1 + mpos[2];
            mseg[3] = g0 + g1 + g2 + mpos[3];
            mh[0] = 0; mh[1] = 0; mh[2] = 0; mh[3] = 0;   // reuse as cursors
        }
        __syncthreads();
        const unsigned char* elem = smem;
        long long vend = e1 & ~3LL;
        for (long long p = e0 + (long long)t * 4; p + 4 <= vend; p += (long long)THR * 4) {
            int4   s4 = *(const int4*)(ei + p);
            int4   r4 = *(const int4*)(ei + n_edges + p);
            float4 x4 = *(const float4*)(x + p);
            float4 p0 = pt[elem[s4.x] * n_elem + elem[r4.x]];
            float4 p1 = pt[elem[s4.y] * n_elem + elem[r4.y]];
            float4 p2 = pt[elem[s4.z] * n_elem + elem[r4.z]];
            float4 p3 = pt[elem[s4.w] * n_elem + elem[r4.w]];
            scatter_bal((unsigned)r4.x, x4.x, p0, mh, mseg, packedB, lane);
            scatter_bal((unsigned)r4.y, x4.y, p1, mh, mseg, packedB, lane);
            scatter_bal((unsigned)r4.z, x4.z, p2, mh, mseg, packedB, lane);
            scatter_bal((unsigned)r4.w, x4.w, p3, mh, mseg, packedB, lane);
        }
        for (long long e2 = vend + t; e2 < e1; e2 += THR) {
            int rr = ei[n_edges + e2];
            float4 pp = pt[elem[ei[e2]] * n_elem + elem[rr]];
            scatter_bal((unsigned)rr, x[e2], pp, mh, mseg, packedB, lane);
        }
    }
    grid_bar(bar, 3 * GRID_B);                       // S3

    // ---------- P3: balanced bucketed scan, LDS f32 accumulator ----------
    int nb0, nb1, nb2, nb3, st1, st2, st3;
    long long cs1, cs2, cs3, g0, g1, g2, g3;
    scan_alloc(gcount, nb0, nb1, nb2, nb3, st1, st2, st3, cs1, cs2, cs3, g0, g1, g2, g3);
    {
        float* acc = (float*)smem;
        for (int i = t * 4; i < P2_CHUNK; i += THR * 4)
            *(float4*)&acc[i] = make_float4(0.f, 0.f, 0.f, 0.f);

        int c   = (b >= st1) + (b >= st2) + (b >= st3);
        int jb  = b - ((c == 0) ? 0 : (c == 1) ? st1 : (c == 2) ? st2 : st3);
        long long gc  = (c == 0) ? g0 : (c == 1) ? g1 : (c == 2) ? g2 : g3;
        int nbc       = (c == 0) ? nb0 : (c == 1) ? nb1 : (c == 2) ? nb2 : nb3;
        long long csc = (c == 0) ? 0LL : (c == 1) ? cs1 : (c == 2) ? cs2 : cs3;
        long long s = csc + gc * jb / nbc;
        long long e = csc + gc * (jb + 1) / nbc;
        __syncthreads();

        long long va = (s + 3) & ~3LL; if (va > e) va = e;
        long long ve = e & ~3LL;       if (ve < va) ve = va;
        for (long long i2 = s + t; i2 < va; i2 += THR) { unsigned w = packedB[i2]; ACC1(w); }
        const long long T4 = (long long)THR * 4;
        long long niter = (ve - va) / (T4 * 4);
        long long base  = va + (long long)t * 4;
        for (long long it = 0; it < niter; ++it, base += T4 * 4) {
            uint4 q0 = *(const uint4*)(packedB + base);
            uint4 q1 = *(const uint4*)(packedB + base + T4);
            uint4 q2 = *(const uint4*)(packedB + base + 2 * T4);
            uint4 q3 = *(const uint4*)(packedB + base + 3 * T4);
            ACC4(q0); ACC4(q1); ACC4(q2); ACC4(q3);
        }
        long long rem0 = va + niter * T4 * 4;
        for (long long b2 = rem0 + (long long)t * 4; b2 + 4 <= ve; b2 += T4) {
            uint4 q = *(const uint4*)(packedB + b2);
            ACC4(q);
        }
        for (long long i2 = ve + t; i2 < e; i2 += THR) { unsigned w = packedB[i2]; ACC1(w); }

        __syncthreads();
        float* pp = partial + (size_t)b * P2_CHUNK;
        for (int i = t * 4; i < P2_CHUNK; i += THR * 4)
            *(float4*)(pp + i) = *(const float4*)&acc[i];
    }
    grid_bar(bar, 4 * GRID_B);                       // S4

    // ---------- P4: reduce partials per node ----------
    for (int i = b * THR + t; i < n_nodes; i += GRID_B * THR) {
        int c  = i >> P2_SHIFT;
        int li = i & (P2_CHUNK - 1);
        int st  = (c == 0) ? 0 : (c == 1) ? st1 : (c == 2) ? st2 : st3;
        int nbc = (c == 0) ? nb0 : (c == 1) ? nb1 : (c == 2) ? nb2 : nb3;
        const float* p = partial + (size_t)st * P2_CHUNK + li;
        float s0 = 0.f, s1 = 0.f, s2 = 0.f, s3 = 0.f;
        int j = 0;
        for (; j + 4 <= nbc; j += 4) {
            s0 += p[(size_t)(j + 0) * P2_CHUNK];
            s1 += p[(size_t)(j + 1) * P2_CHUNK];
            s2 += p[(size_t)(j + 2) * P2_CHUNK];
            s3 += p[(size_t)(j + 3) * P2_CHUNK];
        }
        for (; j < nbc; ++j) s0 += p[(size_t)j * P2_CHUNK];
        out[i] = (s0 + s1) + (s2 + s3);
    }
}

// ================= fallback path: node float4 table + direct device atomics =================
__global__ void zbl_node_prep(const float* __restrict__ node_attrs,
                              const int* __restrict__ atomic_numbers,
                              const float* __restrict__ covalent_radii,
                              float4* __restrict__ node_data,
                              float* __restrict__ out_zero,
                              int n_nodes, int n_elem) {
    int n = blockIdx.x * blockDim.x + threadIdx.x;
    if (n >= n_nodes) return;
    const float* row = node_attrs + (size_t)n * n_elem;
    float best = row[0];
    int bi = 0;
    for (int i = 1; i < n_elem; ++i) {
        float v = row[i];
        if (v > best) { best = v; bi = i; }
    }
    int Z = atomic_numbers[bi];
    float zf = (float)Z;
    node_data[n] = make_float4(zf, __powf(zf, 0.3f), covalent_radii[Z], 0.0f);
    out_zero[n] = 0.0f;
}

__global__ void zbl_edge_atomic(const float* __restrict__ x,
                                const int* __restrict__ edge_index,
                                const float4* __restrict__ node_data,
                                float* __restrict__ out,
                                int n_edges) {
    int e = blockIdx.x * blockDim.x + threadIdx.x;
    if (e >= n_edges) return;
    int snd = edge_index[e];
    int r = edge_index[n_edges + e];
    float xv = x[e];
    float4 du = node_data[snd];
    float4 dv = node_data[r];
    float rmax = du.z + dv.z;
    if (xv >= rmax) return;
    const float inv_a_pref = 1.0f / (0.4543f * 0.529f);
    float t = xv * (du.y + dv.y) * inv_a_pref;
    float phi = 0.1818f  * __expf(-3.2f    * t)
              + 0.5099f  * __expf(-0.9423f * t)
              + 0.2802f  * __expf(-0.4028f * t)
              + 0.02817f * __expf(-0.2016f * t);
    float v = KE_CONST * du.x * dv.x * phi / xv;
    float rr = xv / rmax;
    float r2 = rr * rr;
    float r6 = r2 * r2 * r2;
    float env = 1.0f - 28.0f * r6 + 48.0f * r6 * rr - 21.0f * r6 * r2;
    atomicAdd(&out[r], 0.5f * v * env);
}

extern "C" void kernel_launch(void* const* d_in, const int* in_sizes, int n_in,
                              void* d_out, int out_size, void* d_ws, size_t ws_size,
                              hipStream_t stream) {
    const float* x              = (const float*)d_in[0];
    const float* node_attrs     = (const float*)d_in[1];
    const int*   edge_index     = (const int*)d_in[2];
    const int*   atomic_numbers = (const int*)d_in[3];
    const float* covalent_radii = (const float*)d_in[4];
    float* out = (float*)d_out;

    int n_edges = in_sizes[0];
    int n_elem  = in_sizes[3];
    int n_nodes = in_sizes[1] / n_elem;

    int C = (n_nodes + P2_CHUNK - 1) >> P2_SHIFT;
    size_t elem_bytes   = (((size_t)n_nodes) + 255) & ~(size_t)255;
    size_t meta_bytes   = 256;
    size_t packed_bytes = (((size_t)n_edges * sizeof(unsigned)) + 255) & ~(size_t)255;
    size_t part_bytes   = (size_t)GRID_B * P2_CHUNK * sizeof(float);
    bool fast = (C >= 1) && (C <= MAXC) && (n_nodes <= ELEM_CAP) &&
                (n_elem >= 1) && (n_elem <= MAXE) &&
                (ws_size >= elem_bytes + meta_bytes + packed_bytes + part_bytes);

    if (fast) {
        unsigned char* elem    = (unsigned char*)d_ws;
        unsigned*      meta    = (unsigned*)((char*)d_ws + elem_bytes);
        unsigned*      packedB = (unsigned*)((char*)d_ws + elem_bytes + meta_bytes);
        float*         part    = (float*)((char*)d_ws + elem_bytes + meta_bytes + packed_bytes);

        hipMemsetAsync(meta, 0, meta_bytes, stream);   // gcount + barrier counter
        zbl_fused<<<GRID_B, THR, 0, stream>>>(
            x, node_attrs, edge_index, atomic_numbers, covalent_radii,
            elem, meta, packedB, part, out, n_edges, n_elem, n_nodes);
        return;
    }

    // fallback: node table + plain device atomics
    float4* node_data = (float4*)d_ws;
    zbl_node_prep<<<(n_nodes + 255) / 256, 256, 0, stream>>>(
        node_attrs, atomic_numbers, covalent_radii, node_data,
        out, n_nodes, n_elem);
    zbl_edge_atomic<<<(n_edges + 255) / 256, 256, 0, stream>>>(
        x, edge_index, node_data, out, n_edges);
}

// Round 4
// 177.560 us; speedup vs baseline: 4.0008x; 4.0008x over previous
//
#include <hip/hip_runtime.h>

#define KE_CONST 14.3996454784255f

#define P2_SHIFT 15
#define P2_CHUNK 32768            // 128 KB LDS accumulator per chunk (scan phase)
#define MAXC     4
#define MAXE     16               // pair table up to 256 entries (4 KB LDS)
#define ELEM_CAP 131072           // 128 KB LDS elem table cap
#define CNT_B    256              // count blocks (== DN_BLOCKS, same slice formula)
#define EB       32               // elem-argmax blocks
#define DN_THR   1024
#define DN_BLOCKS 256
#define SCAN_THR 1024
#define SCAN_B   256              // balanced scan blocks (1/CU)

// ---------------- deterministic proportional block allocation for the scan ----------
// Pure function of gcount[0..3]; called identically by scan and reduce kernels.
__device__ __forceinline__ void scan_alloc(const unsigned* __restrict__ g_,
        int& nb0, int& nb1, int& nb2, int& nb3,
        int& st1, int& st2, int& st3,
        long long& cs1, long long& cs2, long long& cs3,
        long long& g0, long long& g1, long long& g2, long long& g3) {
    g0 = g_[0]; g1 = g_[1]; g2 = g_[2]; g3 = g_[3];
    long long tot = g0 + g1 + g2 + g3; if (tot < 1) tot = 1;
    nb0 = (int)((g0 * SCAN_B) / tot); if (nb0 < 1) nb0 = 1;
    nb1 = (int)((g1 * SCAN_B) / tot); if (nb1 < 1) nb1 = 1;
    nb2 = (int)((g2 * SCAN_B) / tot); if (nb2 < 1) nb2 = 1;
    nb3 = (int)((g3 * SCAN_B) / tot); if (nb3 < 1) nb3 = 1;
    int sum = nb0 + nb1 + nb2 + nb3;
    while (sum > SCAN_B) {
        if      (nb0 >= nb1 && nb0 >= nb2 && nb0 >= nb3) nb0--;
        else if (nb1 >= nb2 && nb1 >= nb3)               nb1--;
        else if (nb2 >= nb3)                             nb2--;
        else                                             nb3--;
        sum--;
    }
    while (sum < SCAN_B) {
        if      (nb0 >= nb1 && nb0 >= nb2 && nb0 >= nb3) nb0++;
        else if (nb1 >= nb2 && nb1 >= nb3)               nb1++;
        else if (nb2 >= nb3)                             nb2++;
        else                                             nb3++;
        sum++;
    }
    st1 = nb0; st2 = nb0 + nb1; st3 = nb0 + nb1 + nb2;
    cs1 = g0;  cs2 = g0 + g1;   cs3 = g0 + g1 + g2;
}

// ---------------- per-edge bf16 value from pair-table entry ----------------
__device__ __forceinline__ unsigned enc_val16(float xv, const float4& p) {
    float t = xv * p.x;
    float phi = 0.1818f  * __expf(-3.2f    * t)
              + 0.5099f  * __expf(-0.9423f * t)
              + 0.2802f  * __expf(-0.4028f * t)
              + 0.02817f * __expf(-0.2016f * t);
    float rr = xv * p.w;
    float r2 = rr * rr;
    float r6 = r2 * r2 * r2;
    float env = 1.0f - 28.0f * r6 + 48.0f * r6 * rr - 21.0f * r6 * r2;
    float val = fmaxf(p.y * phi / xv * env, 0.0f);     // clamp r->1 cancellation negatives
    unsigned e = (__float_as_uint(val) + 0x8000u) >> 16;   // round-to-nearest bf16
    return (xv < p.z) ? e : 0u;
}

// ---------------- wave-aggregated bucketed scatter (<=4 LDS atomics / wave-round) ----
__device__ __forceinline__ void scatter_bal(unsigned rw, float xv, const float4& p,
                                            unsigned* cur, const unsigned* seg,
                                            unsigned* __restrict__ packedB, int lane) {
    unsigned cc = rw >> P2_SHIFT;
    unsigned w  = ((rw & (P2_CHUNK - 1)) << 16) | enc_val16(xv, p);
    unsigned long long m0 = __ballot(cc == 0), m1 = __ballot(cc == 1),
                       m2 = __ballot(cc == 2), m3 = __ballot(cc == 3);
    unsigned long long mine = (cc == 0) ? m0 : (cc == 1) ? m1 : (cc == 2) ? m2 : m3;
    int ldr = __ffsll((long long)mine) - 1;
    unsigned base = 0;
    if (lane == ldr) base = atomicAdd(&cur[cc], (unsigned)__popcll(mine));
    base = __shfl(base, ldr, 64);
    unsigned pos = base + (unsigned)__popcll(mine & ((1ull << lane) - 1ull));
    packedB[(size_t)seg[cc] + pos] = w;
}

// zero-mask: ~30% of words encode bf16 0 (env cutoff) — skip the DS RMW entirely.
#define ACC1(W) { if ((W) & 0xFFFFu) \
    atomicAdd(&acc[(W) >> 16], __uint_as_float(((W) & 0xFFFFu) << 16)); }
#define ACC4(Q) { ACC1((Q).x); ACC1((Q).y); ACC1((Q).z); ACC1((Q).w); }

// ---------------- dispatch 1: count (blocks 0..255) + elem argmax (256..287) + pairs (288) ----
__global__ __launch_bounds__(1024)
void zbl_prep(const float* __restrict__ node_attrs,
              const int* __restrict__ ei,
              const int* __restrict__ atomic_numbers,
              const float* __restrict__ covalent_radii,
              unsigned char* __restrict__ elem_g,
              float4* __restrict__ pair_tab,
              unsigned* __restrict__ gcount,
              unsigned* __restrict__ blkpos,
              int n_edges, int n_elem, int n_nodes) {
    const int b = blockIdx.x, t = threadIdx.x, lane = t & 63;

    if (b < CNT_B) {
        // ---- receiver-chunk histogram for this block's edge slice ----
        __shared__ unsigned h[MAXC];
        if (t < MAXC) h[t] = 0u;
        __syncthreads();
        long long e0 = (((long long)b * n_edges) / CNT_B) & ~3LL;
        long long e1 = (b == CNT_B - 1) ? (long long)n_edges
                     : ((((long long)(b + 1) * n_edges) / CNT_B) & ~3LL);
        const int* r = ei + n_edges;
        unsigned c0 = 0, c1 = 0, c2 = 0, c3 = 0;
        long long vend = e1 & ~3LL;
        for (long long p = e0 + (long long)t * 4; p + 4 <= vend; p += 1024LL * 4) {
            int4 a = *(const int4*)(r + p);
            unsigned cc;
            cc = ((unsigned)a.x) >> P2_SHIFT; c0 += (cc==0); c1 += (cc==1); c2 += (cc==2); c3 += (cc==3);
            cc = ((unsigned)a.y) >> P2_SHIFT; c0 += (cc==0); c1 += (cc==1); c2 += (cc==2); c3 += (cc==3);
            cc = ((unsigned)a.z) >> P2_SHIFT; c0 += (cc==0); c1 += (cc==1); c2 += (cc==2); c3 += (cc==3);
            cc = ((unsigned)a.w) >> P2_SHIFT; c0 += (cc==0); c1 += (cc==1); c2 += (cc==2); c3 += (cc==3);
        }
        for (long long e2 = vend + t; e2 < e1; e2 += 1024) {
            unsigned cc = ((unsigned)r[e2]) >> P2_SHIFT;
            c0 += (cc==0); c1 += (cc==1); c2 += (cc==2); c3 += (cc==3);
        }
        for (int o = 32; o; o >>= 1) {
            c0 += __shfl_down(c0, o, 64); c1 += __shfl_down(c1, o, 64);
            c2 += __shfl_down(c2, o, 64); c3 += __shfl_down(c3, o, 64);
        }
        if (lane == 0) {
            atomicAdd(&h[0], c0); atomicAdd(&h[1], c1);
            atomicAdd(&h[2], c2); atomicAdd(&h[3], c3);
        }
        __syncthreads();
        if (t < MAXC)
            blkpos[b * MAXC + t] = atomicAdd(&gcount[t], h[t]);
    } else if (b < CNT_B + EB) {
        // ---- per-node element id (argmax over attrs) ----
        int bb = b - CNT_B;
        int n0 = (int)(((long long)bb * n_nodes) / EB);
        int n1 = (int)(((long long)(bb + 1) * n_nodes) / EB);
        for (int n = n0 + t; n < n1; n += 1024) {
            const float* row = node_attrs + (size_t)n * n_elem;
            float best = row[0]; int bi = 0;
            for (int i = 1; i < n_elem; ++i) {
                float v = row[i];
                if (v > best) { best = v; bi = i; }
            }
            elem_g[n] = (unsigned char)bi;
        }
    } else {
        // ---- n_elem^2 pair table ----
        int np = n_elem * n_elem;
        if (t < np) {
            int eu = t / n_elem, ev = t - eu * n_elem;
            int Zu = atomic_numbers[eu], Zv = atomic_numbers[ev];
            float zu = (float)Zu, zv = (float)Zv;
            float inv_a = (__powf(zu, 0.3f) + __powf(zv, 0.3f)) * (1.0f / (0.4543f * 0.529f));
            float rmax  = covalent_radii[Zu] + covalent_radii[Zv];
            pair_tab[t] = make_float4(inv_a, 0.5f * KE_CONST * zu * zv, rmax, 1.0f / rmax);
        }
    }
}

// ---------------- dispatch 2: dense compute + bucketed scatter ----------------
__global__ __launch_bounds__(DN_THR)
void zbl_dense(const float* __restrict__ x,
               const int* __restrict__ ei,
               const unsigned char* __restrict__ elem_g,
               const float4* __restrict__ pair_tab,
               const unsigned* __restrict__ gcount,
               const unsigned* __restrict__ blkpos,
               unsigned* __restrict__ packedB,
               int n_edges, int n_elem, int n_nodes) {
    __shared__ __align__(16) unsigned char elem[ELEM_CAP];
    __shared__ float4 pt[MAXE * MAXE];
    __shared__ unsigned cur[MAXC];
    __shared__ unsigned seg[MAXC];

    const int b = blockIdx.x, t = threadIdx.x, lane = t & 63;
    if (t == 0) {
        unsigned G0 = gcount[0], G1 = gcount[1], G2 = gcount[2];
        seg[0] = blkpos[b * MAXC + 0];
        seg[1] = G0 + blkpos[b * MAXC + 1];
        seg[2] = G0 + G1 + blkpos[b * MAXC + 2];
        seg[3] = G0 + G1 + G2 + blkpos[b * MAXC + 3];
        cur[0] = 0; cur[1] = 0; cur[2] = 0; cur[3] = 0;
    }
    int np = n_elem * n_elem;
    for (int i = t; i < np; i += DN_THR) pt[i] = pair_tab[i];
    {
        int nwords = (n_nodes + 15) >> 4;
        const uint4* eg4 = (const uint4*)elem_g;
        uint4* el4 = (uint4*)elem;
        for (int i = t; i < nwords; i += DN_THR) el4[i] = eg4[i];
    }
    __syncthreads();

    long long e0 = (((long long)b * n_edges) / DN_BLOCKS) & ~3LL;
    long long e1 = (b == DN_BLOCKS - 1) ? (long long)n_edges
                 : ((((long long)(b + 1) * n_edges) / DN_BLOCKS) & ~3LL);
    long long vend = e1 & ~3LL;

    for (long long p = e0 + (long long)t * 4; p + 4 <= vend; p += (long long)DN_THR * 4) {
        int4   s4 = *(const int4*)(ei + p);
        int4   r4 = *(const int4*)(ei + n_edges + p);
        float4 x4 = *(const float4*)(x + p);
        float4 p0 = pt[elem[s4.x] * n_elem + elem[r4.x]];
        float4 p1 = pt[elem[s4.y] * n_elem + elem[r4.y]];
        float4 p2 = pt[elem[s4.z] * n_elem + elem[r4.z]];
        float4 p3 = pt[elem[s4.w] * n_elem + elem[r4.w]];
        scatter_bal((unsigned)r4.x, x4.x, p0, cur, seg, packedB, lane);
        scatter_bal((unsigned)r4.y, x4.y, p1, cur, seg, packedB, lane);
        scatter_bal((unsigned)r4.z, x4.z, p2, cur, seg, packedB, lane);
        scatter_bal((unsigned)r4.w, x4.w, p3, cur, seg, packedB, lane);
    }
    for (long long e2 = vend + t; e2 < e1; e2 += DN_THR) {
        int rr = ei[n_edges + e2];
        float4 pp = pt[elem[ei[e2]] * n_elem + elem[rr]];
        scatter_bal((unsigned)rr, x[e2], pp, cur, seg, packedB, lane);
    }
}

// ---------------- dispatch 3: balanced bucketed scan ----------------
__global__ __launch_bounds__(SCAN_THR)
void zbl_scan_bal(const unsigned* __restrict__ packedB,
                  const unsigned* __restrict__ gcount,
                  float* __restrict__ partial) {
    __shared__ __align__(16) float acc[P2_CHUNK];
    const int b = blockIdx.x, t = threadIdx.x;

    int nb0, nb1, nb2, nb3, st1, st2, st3;
    long long cs1, cs2, cs3, g0, g1, g2, g3;
    scan_alloc(gcount, nb0, nb1, nb2, nb3, st1, st2, st3, cs1, cs2, cs3, g0, g1, g2, g3);

    for (int i = t * 4; i < P2_CHUNK; i += SCAN_THR * 4)
        *(float4*)&acc[i] = make_float4(0.f, 0.f, 0.f, 0.f);
    __syncthreads();

    int c   = (b >= st1) + (b >= st2) + (b >= st3);
    int jb  = b - ((c == 0) ? 0 : (c == 1) ? st1 : (c == 2) ? st2 : st3);
    long long gc  = (c == 0) ? g0 : (c == 1) ? g1 : (c == 2) ? g2 : g3;
    int nbc       = (c == 0) ? nb0 : (c == 1) ? nb1 : (c == 2) ? nb2 : nb3;
    long long csc = (c == 0) ? 0LL : (c == 1) ? cs1 : (c == 2) ? cs2 : cs3;
    long long s = csc + gc * jb / nbc;
    long long e = csc + gc * (jb + 1) / nbc;

    long long va = (s + 3) & ~3LL; if (va > e) va = e;
    long long ve = e & ~3LL;       if (ve < va) ve = va;
    for (long long i2 = s + t; i2 < va; i2 += SCAN_THR) { unsigned w = packedB[i2]; ACC1(w); }
    const long long T4 = (long long)SCAN_THR * 4;
    long long niter = (ve - va) / (T4 * 4);
    long long base  = va + (long long)t * 4;
    for (long long it = 0; it < niter; ++it, base += T4 * 4) {
        uint4 q0 = *(const uint4*)(packedB + base);
        uint4 q1 = *(const uint4*)(packedB + base + T4);
        uint4 q2 = *(const uint4*)(packedB + base + 2 * T4);
        uint4 q3 = *(const uint4*)(packedB + base + 3 * T4);
        ACC4(q0); ACC4(q1); ACC4(q2); ACC4(q3);
    }
    long long rem0 = va + niter * T4 * 4;
    for (long long b2 = rem0 + (long long)t * 4; b2 + 4 <= ve; b2 += T4) {
        uint4 q = *(const uint4*)(packedB + b2);
        ACC4(q);
    }
    for (long long i2 = ve + t; i2 < e; i2 += SCAN_THR) { unsigned w = packedB[i2]; ACC1(w); }

    __syncthreads();
    float* pp = partial + (size_t)b * P2_CHUNK;
    for (int i = t * 4; i < P2_CHUNK; i += SCAN_THR * 4)
        *(float4*)(pp + i) = *(const float4*)&acc[i];
}

// ---------------- dispatch 4: reduce per-chunk partials per node ----------------
__global__ void zbl_reduce_bal(const float* __restrict__ partial,
                               const unsigned* __restrict__ gcount,
                               float* __restrict__ out,
                               int n_nodes) {
    int i = blockIdx.x * blockDim.x + threadIdx.x;
    if (i >= n_nodes) return;

    int nb0, nb1, nb2, nb3, st1, st2, st3;
    long long cs1, cs2, cs3, g0, g1, g2, g3;
    scan_alloc(gcount, nb0, nb1, nb2, nb3, st1, st2, st3, cs1, cs2, cs3, g0, g1, g2, g3);

    int c  = i >> P2_SHIFT;
    int li = i & (P2_CHUNK - 1);
    int st  = (c == 0) ? 0 : (c == 1) ? st1 : (c == 2) ? st2 : st3;
    int nbc = (c == 0) ? nb0 : (c == 1) ? nb1 : (c == 2) ? nb2 : nb3;
    const float* p = partial + (size_t)st * P2_CHUNK + li;
    float s0 = 0.f, s1 = 0.f, s2 = 0.f, s3 = 0.f;
    int j = 0;
    for (; j + 4 <= nbc; j += 4) {
        s0 += p[(size_t)(j + 0) * P2_CHUNK];
        s1 += p[(size_t)(j + 1) * P2_CHUNK];
        s2 += p[(size_t)(j + 2) * P2_CHUNK];
        s3 += p[(size_t)(j + 3) * P2_CHUNK];
    }
    for (; j < nbc; ++j) s0 += p[(size_t)j * P2_CHUNK];
    out[i] = (s0 + s1) + (s2 + s3);
}

// ================= fallback path: node float4 table + direct device atomics =================
__global__ void zbl_node_prep(const float* __restrict__ node_attrs,
                              const int* __restrict__ atomic_numbers,
                              const float* __restrict__ covalent_radii,
                              float4* __restrict__ node_data,
                              float* __restrict__ out_zero,
                              int n_nodes, int n_elem) {
    int n = blockIdx.x * blockDim.x + threadIdx.x;
    if (n >= n_nodes) return;
    const float* row = node_attrs + (size_t)n * n_elem;
    float best = row[0];
    int bi = 0;
    for (int i = 1; i < n_elem; ++i) {
        float v = row[i];
        if (v > best) { best = v; bi = i; }
    }
    int Z = atomic_numbers[bi];
    float zf = (float)Z;
    node_data[n] = make_float4(zf, __powf(zf, 0.3f), covalent_radii[Z], 0.0f);
    out_zero[n] = 0.0f;
}

__global__ void zbl_edge_atomic(const float* __restrict__ x,
                                const int* __restrict__ edge_index,
                                const float4* __restrict__ node_data,
                                float* __restrict__ out,
                                int n_edges) {
    int e = blockIdx.x * blockDim.x + threadIdx.x;
    if (e >= n_edges) return;
    int snd = edge_index[e];
    int r = edge_index[n_edges + e];
    float xv = x[e];
    float4 du = node_data[snd];
    float4 dv = node_data[r];
    float rmax = du.z + dv.z;
    if (xv >= rmax) return;
    const float inv_a_pref = 1.0f / (0.4543f * 0.529f);
    float t = xv * (du.y + dv.y) * inv_a_pref;
    float phi = 0.1818f  * __expf(-3.2f    * t)
              + 0.5099f  * __expf(-0.9423f * t)
              + 0.2802f  * __expf(-0.4028f * t)
              + 0.02817f * __expf(-0.2016f * t);
    float v = KE_CONST * du.x * dv.x * phi / xv;
    float rr = xv / rmax;
    float r2 = rr * rr;
    float r6 = r2 * r2 * r2;
    float env = 1.0f - 28.0f * r6 + 48.0f * r6 * rr - 21.0f * r6 * r2;
    atomicAdd(&out[r], 0.5f * v * env);
}

extern "C" void kernel_launch(void* const* d_in, const int* in_sizes, int n_in,
                              void* d_out, int out_size, void* d_ws, size_t ws_size,
                              hipStream_t stream) {
    const float* x              = (const float*)d_in[0];
    const float* node_attrs     = (const float*)d_in[1];
    const int*   edge_index     = (const int*)d_in[2];
    const int*   atomic_numbers = (const int*)d_in[3];
    const float* covalent_radii = (const float*)d_in[4];
    float* out = (float*)d_out;

    int n_edges = in_sizes[0];
    int n_elem  = in_sizes[3];
    int n_nodes = in_sizes[1] / n_elem;

    int C = (n_nodes + P2_CHUNK - 1) >> P2_SHIFT;
    size_t elem_bytes   = (((size_t)n_nodes) + 255) & ~(size_t)255;
    size_t pair_bytes   = ((size_t)MAXE * MAXE * sizeof(float4) + 255) & ~(size_t)255;
    size_t meta_bytes   = (((size_t)(16 + CNT_B * MAXC) * 4) + 255) & ~(size_t)255;
    size_t packed_bytes = (((size_t)n_edges * sizeof(unsigned)) + 255) & ~(size_t)255;
    size_t part_bytes   = (size_t)SCAN_B * P2_CHUNK * sizeof(float);
    bool fast = (C >= 1) && (C <= MAXC) && (n_nodes <= ELEM_CAP) &&
                (n_elem >= 1) && (n_elem <= MAXE) &&
                (ws_size >= elem_bytes + pair_bytes + meta_bytes + packed_bytes + part_bytes);

    if (fast) {
        unsigned char* elem     = (unsigned char*)d_ws;
        float4*        pair_tab = (float4*)((char*)d_ws + elem_bytes);
        unsigned*      gcount   = (unsigned*)((char*)d_ws + elem_bytes + pair_bytes);
        unsigned*      blkpos   = gcount + 16;
        unsigned*      packedB  = (unsigned*)((char*)d_ws + elem_bytes + pair_bytes + meta_bytes);
        float*         part     = (float*)((char*)d_ws + elem_bytes + pair_bytes + meta_bytes + packed_bytes);

        hipMemsetAsync(gcount, 0, 64, stream);   // zero bucket counters only

        zbl_prep<<<CNT_B + EB + 1, 1024, 0, stream>>>(
            node_attrs, edge_index, atomic_numbers, covalent_radii,
            elem, pair_tab, gcount, blkpos, n_edges, n_elem, n_nodes);

        zbl_dense<<<DN_BLOCKS, DN_THR, 0, stream>>>(
            x, edge_index, elem, pair_tab, gcount, blkpos, packedB,
            n_edges, n_elem, n_nodes);

        zbl_scan_bal<<<SCAN_B, SCAN_THR, 0, stream>>>(packedB, gcount, part);

        zbl_reduce_bal<<<(n_nodes + 255) / 256, 256, 0, stream>>>(
            part, gcount, out, n_nodes);
        return;
    }

    // fallback: node table + plain device atomics
    float4* node_data = (float4*)d_ws;
    zbl_node_prep<<<(n_nodes + 255) / 256, 256, 0, stream>>>(
        node_attrs, atomic_numbers, covalent_radii, node_data,
        out, n_nodes, n_elem);
    zbl_edge_atomic<<<(n_edges + 255) / 256, 256, 0, stream>>>(
        x, edge_index, node_data, out, n_edges);
}